// Round 8
// baseline (733.837 us; speedup 1.0000x reference)
//
#include <hip/hip_runtime.h>
#include <cmath>

using bf16x8 = __attribute__((ext_vector_type(8))) short;
using f32x16 = __attribute__((ext_vector_type(16))) float;

// ---------- helpers ----------
__device__ __forceinline__ short f2bf_rne(float f) {
    union { float f; unsigned u; } a; a.f = f;
    unsigned r = a.u + 0x7fffu + ((a.u >> 16) & 1u);
    return (short)(r >> 16);
}
__device__ __forceinline__ float bf2f(short s) {
    union { unsigned u; float f; } a;
    a.u = ((unsigned)(unsigned short)s) << 16;
    return a.f;
}
__device__ __forceinline__ void gld16(void* lds, const void* g) {
    __builtin_amdgcn_global_load_lds(
        (const __attribute__((address_space(1))) unsigned int*)g,
        (__attribute__((address_space(3))) unsigned int*)lds, 16, 0, 0);
}

// ========= Layouts =========
// A-blob (slot-major, unswizzled; read direct global->reg):
//   addr(kt, slot, m) = ((kt*8 + slot)*Mc + m)*16 bytes, slot = 2*q + isLo,
//   q = k-octet within kt (k_real = kt*32 + q*8 + e). 1-kt pad (33 slots of 8).
// W-blob: per (g,nt,kt) 32KB pre-swizzled image (slot s holds octet-pair
//   s^(row&7)) so linear global_load_lds yields conflict-free ds_read_b128.
//   kt stride padded to 35 so kt+3 prefetch stays in-bounds.

// ---------- convert x -> A blob ----------
__global__ __launch_bounds__(256)
void bru_conv_a(const float* __restrict__ x, char* __restrict__ Ablob,
                int T, int D, int Tc, int t0, int Mc)
{
    const int idx = blockIdx.x * 256 + threadIdx.x;   // Mc*32 threads
    const int kt = idx / Mc;
    const int m  = idx - kt * Mc;

    const long xrow = (long)(m / Tc) * T + t0 + (m % Tc);
    const float* src = x + xrow * (long)D + kt * 32;

    float v[32];
    #pragma unroll
    for (int i = 0; i < 8; ++i)
        *(float4*)&v[i * 4] = *(const float4*)(src + i * 4);

    #pragma unroll
    for (int q = 0; q < 4; ++q) {
        short hi[8], lo[8];
        #pragma unroll
        for (int j = 0; j < 8; ++j) {
            float f = v[q * 8 + j];
            hi[j] = f2bf_rne(f);
            lo[j] = f2bf_rne(f - bf2f(hi[j]));
        }
        char* b0 = Ablob + ((size_t)(kt * 8 + 2 * q) * Mc + m) * 16;
        char* b1 = Ablob + ((size_t)(kt * 8 + 2 * q + 1) * Mc + m) * 16;
        *(bf16x8*)b0 = *(bf16x8*)hi;
        *(bf16x8*)b1 = *(bf16x8*)lo;
    }
}

// ---------- convert W (3 gates) -> B blobs ----------
__global__ __launch_bounds__(256)
void bru_conv_w(const float* __restrict__ wz, const float* __restrict__ wr,
                const float* __restrict__ wh, short* __restrict__ Wblob,
                int D, int U)
{
    const int gid  = blockIdx.x * 256 + threadIdx.x;
    const int blob = gid >> 10;
    const int idx  = gid & 1023;
    const int row  = idx >> 2;            // u within 256-col tile
    const int q    = idx & 3;

    const int g    = blob >> 7;
    const int rest = blob & 127;
    const int nt   = rest >> 5;
    const int kt   = rest & 31;

    const float* W = (g == 0) ? wz : (g == 1) ? wr : wh;
    const int d0 = kt * 32 + q * 8;
    const int u  = nt * 256 + row;

    short hi[8], lo[8];
    #pragma unroll
    for (int j = 0; j < 8; ++j) {
        float v = W[(long)(d0 + j) * U + u];
        hi[j] = f2bf_rne(v);
        lo[j] = f2bf_rne(v - bf2f(hi[j]));
    }
    short* base = Wblob + ((size_t)((g * 4 + nt) * 35 + kt)) * 16384 + row * 64;
    const int sh = (2 * q) ^ (row & 7);
    *(bf16x8*)(base + sh * 8)       = *(bf16x8*)hi;
    *(bf16x8*)(base + (sh ^ 1) * 8) = *(bf16x8*)lo;
}

// ---------- split-precision 32x32x16 MFMA GEMM ----------
// Block tile 256x256; 8 waves as 4x2 (wave tile 64x128).
// B quad-buffered in LDS (4x32KB, distance-3 prefetch, counted vmcnt(56) fence
// so the barrier only waits on staging issued 2 kt earlier);
// A loaded global->register, refilled mid-kt for kt+1 (compiler use-waits).
__global__ __launch_bounds__(512, 2)
void bru_gemm_mfma(const char* __restrict__ Ablob, const char* __restrict__ Wblob,
                   const float* __restrict__ bz, const float* __restrict__ br,
                   const float* __restrict__ bh,
                   _Float16* __restrict__ proj,
                   int nmt, int U, int Mc)
{
    __shared__ char sm[131072];   // 4 x 32KB B buffers

    const int ngrid = gridDim.x;
    const int bid   = blockIdx.x;
    int lid = bid;
    if ((ngrid & 7) == 0) lid = (bid & 7) * (ngrid >> 3) + (bid >> 3);
    const int mt  = lid / 12;
    const int rem = lid - mt * 12;
    const int g   = rem >> 2;
    const int nt  = rem & 3;

    const int tid  = threadIdx.x;
    const int lane = tid & 63;
    const int w    = tid >> 6;
    const int wm   = w >> 1, wn = w & 1;
    const int l31  = lane & 31;
    const int lhi  = lane >> 5;

    const char* bsrc = (const char*)Wblob + (size_t)((g * 4 + nt) * 35) * 32768;

    const int arow = mt * 256 + wm * 64 + l31;
    const size_t aMc = (size_t)Mc;
#define AADDR(kt_, ks_, i_, lo_) \
    (Ablob + (((size_t)((kt_) * 8 + ((ks_) * 2 + lhi) * 2 + (lo_))) * aMc + (size_t)(arow + (i_) * 32)) * 16)

    const int brow = wn * 128 + l31;
    const int br7  = brow & 7;
#define BOFF(j_, ks_, lo_) \
    ((size_t)(brow + (j_) * 32) * 128 + (size_t)((((((ks_) * 2 + lhi) * 2 + (lo_))) ^ br7) * 16))

    f32x16 acc[2][4];
    #pragma unroll
    for (int i = 0; i < 2; ++i)
        #pragma unroll
        for (int j = 0; j < 4; ++j) acc[i][j] = (f32x16)0.f;

    bf16x8 va[2][2], vb[2][2];

    // prologue: stage B(0..2) -> buf0..2; preload A(0, ks0/ks1)
    #pragma unroll
    for (int b = 0; b < 3; ++b)
        #pragma unroll
        for (int i = 0; i < 4; ++i)
            gld16(sm + b * 32768 + i * 8192 + tid * 16,
                  bsrc + (size_t)b * 32768 + i * 8192 + tid * 16);
    #pragma unroll
    for (int i = 0; i < 2; ++i) {
        va[i][0] = *(const bf16x8*)AADDR(0, 0, i, 0);
        va[i][1] = *(const bf16x8*)AADDR(0, 0, i, 1);
        vb[i][0] = *(const bf16x8*)AADDR(0, 1, i, 0);
        vb[i][1] = *(const bf16x8*)AADDR(0, 1, i, 1);
    }
    __builtin_amdgcn_sched_barrier(0);
    asm volatile("s_waitcnt vmcnt(24)" ::: "memory");   // B(0) in LDS; B1,B2,A in flight
    __builtin_amdgcn_sched_barrier(0);
    __builtin_amdgcn_s_barrier();

    for (int kt = 0; kt < 32; ++kt) {
        const char* buf  = sm + (kt & 3) * 32768;
        char*       bufn = sm + ((kt + 3) & 3) * 32768;
        const char* bsn  = bsrc + (size_t)(kt + 3) * 32768;

        // stage B(kt+3) (pad kts 32..34 exist; never consumed)
        #pragma unroll
        for (int i = 0; i < 4; ++i)
            gld16(bufn + i * 8192 + tid * 16, bsn + i * 8192 + tid * 16);

        // kstep 0 (uses va = A(kt,ks0))
        __builtin_amdgcn_s_setprio(1);
        #pragma unroll
        for (int j = 0; j < 4; ++j) {
            bf16x8 bh_ = *(const bf16x8*)(buf + BOFF(j, 0, 0));
            bf16x8 bl_ = *(const bf16x8*)(buf + BOFF(j, 0, 1));
            acc[0][j] = __builtin_amdgcn_mfma_f32_32x32x16_bf16(va[0][0], bh_, acc[0][j], 0, 0, 0);
            acc[0][j] = __builtin_amdgcn_mfma_f32_32x32x16_bf16(va[0][1], bh_, acc[0][j], 0, 0, 0);
            acc[0][j] = __builtin_amdgcn_mfma_f32_32x32x16_bf16(va[0][0], bl_, acc[0][j], 0, 0, 0);
            acc[1][j] = __builtin_amdgcn_mfma_f32_32x32x16_bf16(va[1][0], bh_, acc[1][j], 0, 0, 0);
            acc[1][j] = __builtin_amdgcn_mfma_f32_32x32x16_bf16(va[1][1], bh_, acc[1][j], 0, 0, 0);
            acc[1][j] = __builtin_amdgcn_mfma_f32_32x32x16_bf16(va[1][0], bl_, acc[1][j], 0, 0, 0);
        }
        __builtin_amdgcn_s_setprio(0);

        // refill va <- A(kt+1, ks0)   (kt=31 reads 1-kt pad; never consumed)
        #pragma unroll
        for (int i = 0; i < 2; ++i) {
            va[i][0] = *(const bf16x8*)AADDR(kt + 1, 0, i, 0);
            va[i][1] = *(const bf16x8*)AADDR(kt + 1, 0, i, 1);
        }

        // kstep 1 (uses vb = A(kt,ks1))
        __builtin_amdgcn_s_setprio(1);
        #pragma unroll
        for (int j = 0; j < 4; ++j) {
            bf16x8 bh_ = *(const bf16x8*)(buf + BOFF(j, 1, 0));
            bf16x8 bl_ = *(const bf16x8*)(buf + BOFF(j, 1, 1));
            acc[0][j] = __builtin_amdgcn_mfma_f32_32x32x16_bf16(vb[0][0], bh_, acc[0][j], 0, 0, 0);
            acc[0][j] = __builtin_amdgcn_mfma_f32_32x32x16_bf16(vb[0][1], bh_, acc[0][j], 0, 0, 0);
            acc[0][j] = __builtin_amdgcn_mfma_f32_32x32x16_bf16(vb[0][0], bl_, acc[0][j], 0, 0, 0);
            acc[1][j] = __builtin_amdgcn_mfma_f32_32x32x16_bf16(vb[1][0], bh_, acc[1][j], 0, 0, 0);
            acc[1][j] = __builtin_amdgcn_mfma_f32_32x32x16_bf16(vb[1][1], bh_, acc[1][j], 0, 0, 0);
            acc[1][j] = __builtin_amdgcn_mfma_f32_32x32x16_bf16(vb[1][0], bl_, acc[1][j], 0, 0, 0);
        }
        __builtin_amdgcn_s_setprio(0);

        // refill vb <- A(kt+1, ks1)
        #pragma unroll
        for (int i = 0; i < 2; ++i) {
            vb[i][0] = *(const bf16x8*)AADDR(kt + 1, 1, i, 0);
            vb[i][1] = *(const bf16x8*)AADDR(kt + 1, 1, i, 1);
        }

        // fence: per kt this wave issues [B:4][va:8][vb:8] = 20 loads.
        // Need only B(kt+1) (staged at kt-2) complete: allow this kt's 20
        // + (kt-1)'s 20 + (kt-2)'s va/vb 16 = 56 outstanding.
        __builtin_amdgcn_sched_barrier(0);
        asm volatile("s_waitcnt vmcnt(56)" ::: "memory");
        __builtin_amdgcn_sched_barrier(0);
        __builtin_amdgcn_s_barrier();
    }
#undef AADDR
#undef BOFF

    // epilogue: C map (m74/m101): col=lane&31, row=(reg&3)+8*(reg>>2)+4*(lane>>5)
    const float* bias = (g == 0) ? bz : (g == 1) ? br : bh;
    float bcol[4];
    #pragma unroll
    for (int j = 0; j < 4; ++j) bcol[j] = bias[nt * 256 + wn * 128 + j * 32 + l31];

    _Float16* cbase = proj + (size_t)g * Mc * U + (size_t)(nt * 256 + wn * 128) + l31;
    #pragma unroll
    for (int i = 0; i < 2; ++i) {
        #pragma unroll
        for (int j = 0; j < 4; ++j) {
            #pragma unroll
            for (int reg = 0; reg < 16; ++reg) {
                const int row = mt * 256 + wm * 64 + i * 32 + (reg & 3) + 8 * (reg >> 2) + 4 * lhi;
                cbase[(size_t)row * U + j * 32] = (_Float16)(acc[i][j][reg] + bcol[j]);
            }
        }
    }
}

// ---------- scan: one thread per (b,u); 8-deep rotating register prefetch ----------
#define PF 8
__global__ __launch_bounds__(256)
void bru_scan(const _Float16* __restrict__ proj,
              const float* __restrict__ mz, const float* __restrict__ mr,
              float* __restrict__ out,
              float* __restrict__ hstate,
              int B, int T, int U, int Tc, int t0, int Mc)
{
    const int idx = blockIdx.x * blockDim.x + threadIdx.x;
    const int b = idx / U;
    const int u = idx - b * U;

    float h = (t0 == 0) ? 0.f : hstate[idx];
    const float vmz = mz[u];
    const float vmr = mr[u];

    const _Float16* pz = proj + (long)b * Tc * U + u;
    const _Float16* pr = pz + (long)Mc * U;
    const _Float16* ph = pr + (long)Mc * U;
    float* po = out + ((long)b * T + t0) * U + u;

    _Float16 fz[PF], fr[PF], fh[PF];
    #pragma unroll
    for (int i = 0; i < PF; ++i) {
        const long o = (long)((i < Tc) ? i : (Tc - 1)) * U;
        fz[i] = pz[o]; fr[i] = pr[o]; fh[i] = ph[o];
    }

    for (int t = 0; t < Tc; t += PF) {
        #pragma unroll
        for (int i = 0; i < PF; ++i) {
            const float xz = (float)fz[i];
            const float xr = (float)fr[i];
            const float xh = (float)fh[i];
            {
                int tn = t + i + PF; if (tn > Tc - 1) tn = Tc - 1;
                const long o = (long)tn * U;
                fz[i] = pz[o]; fr[i] = pr[o]; fh[i] = ph[o];
            }
            const float e2r = __expf(2.f * (xr + h * vmr));
            const float rr  = 2.f - 2.f / (e2r + 1.f);             // tanh(.)+1
            const float zz  = 1.f / (1.f + __expf(-(xz + h * vmz)));
            const float e2h = __expf(2.f * (xh + rr * h));
            const float hh  = 1.f - 2.f / (e2h + 1.f);             // tanh(.)
            h = (1.f - zz) * hh + zz * h;
            if (t + i < Tc) po[(long)(t + i) * U] = h;
        }
    }
    hstate[idx] = h;
}

// ---------- launch ----------
extern "C" void kernel_launch(void* const* d_in, const int* in_sizes, int n_in,
                              void* d_out, int out_size, void* d_ws, size_t ws_size,
                              hipStream_t stream)
{
    const float* x  = (const float*)d_in[0];
    const float* wz = (const float*)d_in[1];
    const float* wr = (const float*)d_in[2];
    const float* wh = (const float*)d_in[3];
    const float* mz = (const float*)d_in[4];
    const float* mr = (const float*)d_in[5];
    const float* bz = (const float*)d_in[6];
    const float* br = (const float*)d_in[7];
    const float* bh = (const float*)d_in[8];

    const int B = 64, T = 512, D = 1024, U = 1024;

    const size_t h_bytes = (size_t)B * U * sizeof(float);
    const size_t w_bytes = (size_t)12 * 35 * 32768;   // W blobs incl. 3-kt pad

    int Tc = T;
    while (Tc > 4) {
        const int Mc_ = B * Tc;
        const size_t a_bytes_ = (size_t)33 * 8 * Mc_ * 16;
        const size_t p_bytes_ = 3ull * Mc_ * U * sizeof(_Float16);
        if (h_bytes + w_bytes + a_bytes_ + p_bytes_ <= ws_size) break;
        Tc >>= 1;
    }
    const int nmt = B * Tc / 256;
    const int Mc  = B * Tc;
    const size_t a_bytes = (size_t)33 * 8 * Mc * 16;

    float*    h_state = (float*)d_ws;
    short*    Wblob   = (short*)((char*)d_ws + h_bytes);
    char*     Ablob   = (char*)d_ws + h_bytes + w_bytes;
    _Float16* proj    = (_Float16*)((char*)d_ws + h_bytes + w_bytes + a_bytes);

    bru_conv_w<<<3 * 4 * 32 * 1024 / 256, 256, 0, stream>>>(wz, wr, wh, Wblob, D, U);

    for (int t0 = 0; t0 < T; t0 += Tc) {
        bru_conv_a<<<(Mc * 32) / 256, 256, 0, stream>>>(x, Ablob, T, D, Tc, t0, Mc);

        bru_gemm_mfma<<<3 * nmt * 4, 512, 0, stream>>>(
            Ablob, (const char*)Wblob, bz, br, bh, proj, nmt, U, Mc);

        bru_scan<<<(B * U) / 256, 256, 0, stream>>>(
            proj, mz, mr, (float*)d_out, h_state, B, T, U, Tc, t0, Mc);
    }
}

// Round 9
// 586.520 us; speedup vs baseline: 1.2512x; 1.2512x over previous
//
#include <hip/hip_runtime.h>
#include <cmath>

using f16x8  = __attribute__((ext_vector_type(8))) _Float16;
using f32x16 = __attribute__((ext_vector_type(16))) float;

// ---------- helpers ----------
__device__ __forceinline__ void gld16(void* lds, const void* g) {
    __builtin_amdgcn_global_load_lds(
        (const __attribute__((address_space(1))) unsigned int*)g,
        (__attribute__((address_space(3))) unsigned int*)lds, 16, 0, 0);
}

// ========= Layouts =========
// A-blob (x split into f16 hi+lo; slot-major, unswizzled; global->reg):
//   addr(kt, slot, m) = ((kt*8 + slot)*Mc + m)*16 bytes, slot = 2*q + isLo,
//   q = k-octet within kt (k_real = kt*32 + q*8 + e). 1-kt pad (33 kts).
// W-blob (single f16): per (g,nt,kt2) 32KB pre-swizzled image covering K=64:
//   256 rows(u) x 8 slots x 16B; stored slot s holds k-octet q = s ^ (row&7)
//   so linear global_load_lds yields conflict-free ds_read_b128.
//   kt2 stride padded to 18 so kt2+2 prefetch stays in-bounds.

// ---------- convert x -> A blob (f16 hi/lo split) ----------
__global__ __launch_bounds__(256)
void bru_conv_a(const float* __restrict__ x, char* __restrict__ Ablob,
                int T, int D, int Tc, int t0, int Mc)
{
    const int idx = blockIdx.x * 256 + threadIdx.x;   // Mc*32 threads
    const int kt = idx / Mc;
    const int m  = idx - kt * Mc;

    const long xrow = (long)(m / Tc) * T + t0 + (m % Tc);
    const float* src = x + xrow * (long)D + kt * 32;

    float v[32];
    #pragma unroll
    for (int i = 0; i < 8; ++i)
        *(float4*)&v[i * 4] = *(const float4*)(src + i * 4);

    #pragma unroll
    for (int q = 0; q < 4; ++q) {
        _Float16 hi[8], lo[8];
        #pragma unroll
        for (int j = 0; j < 8; ++j) {
            float f = v[q * 8 + j];
            hi[j] = (_Float16)f;
            lo[j] = (_Float16)(f - (float)hi[j]);
        }
        char* b0 = Ablob + ((size_t)(kt * 8 + 2 * q) * Mc + m) * 16;
        char* b1 = Ablob + ((size_t)(kt * 8 + 2 * q + 1) * Mc + m) * 16;
        *(f16x8*)b0 = *(f16x8*)hi;
        *(f16x8*)b1 = *(f16x8*)lo;
    }
}

// ---------- convert W (3 gates) -> single-f16 pair-blobs ----------
__global__ __launch_bounds__(256)
void bru_conv_w(const float* __restrict__ wz, const float* __restrict__ wr,
                const float* __restrict__ wh, char* __restrict__ Wblob,
                int D, int U)
{
    const int gid  = blockIdx.x * 256 + threadIdx.x;
    const int blob = gid >> 11;           // 2048 threads per pair-blob
    const int idx  = gid & 2047;
    const int row  = idx >> 3;            // u within 256-col tile
    const int s    = idx & 7;

    const int g    = blob >> 6;           // 4 nt * 16 kt2 = 64 blobs/gate
    const int rest = blob & 63;
    const int nt   = rest >> 4;
    const int kt2  = rest & 15;

    const float* W = (g == 0) ? wz : (g == 1) ? wr : wh;
    const int q  = s ^ (row & 7);
    const int d0 = kt2 * 64 + q * 8;
    const int u  = nt * 256 + row;

    _Float16 o[8];
    #pragma unroll
    for (int j = 0; j < 8; ++j)
        o[j] = (_Float16)W[(long)(d0 + j) * U + u];

    *(f16x8*)(Wblob + ((size_t)((g * 4 + nt) * 18 + kt2)) * 32768 + row * 128 + s * 16)
        = *(f16x8*)o;
}

// ---------- f16 2-product MFMA GEMM ----------
// proj[g][m][u] = sum_d (xh+xl)[m][d] * w_f16[d][u] + bias: 2 MFMA per (i,j,kstep).
// Block 256x256, 8 waves 4x2 (wave tile 64x128). W in LDS (4 x 32KB pair
// buffers, distance-2-pair prefetch, one barrier per pair, counted vmcnt).
// A global->reg, full-kt-ahead double register set.
__global__ __launch_bounds__(512, 2)
void bru_gemm_mfma(const char* __restrict__ Ablob, const char* __restrict__ Wblob,
                   const float* __restrict__ bz, const float* __restrict__ br,
                   const float* __restrict__ bh,
                   _Float16* __restrict__ proj,
                   int nmt, int U, int Mc)
{
    __shared__ char sm[131072];   // 4 x 32KB W pair-buffers

    const int ngrid = gridDim.x;
    const int bid   = blockIdx.x;
    int lid = bid;
    if ((ngrid & 7) == 0) lid = (bid & 7) * (ngrid >> 3) + (bid >> 3);
    const int mt  = lid / 12;
    const int rem = lid - mt * 12;
    const int g   = rem >> 2;
    const int nt  = rem & 3;

    const int tid  = threadIdx.x;
    const int lane = tid & 63;
    const int w    = tid >> 6;
    const int wm   = w >> 1, wn = w & 1;   // 4x2 wave grid; wave tile 64x128
    const int l31  = lane & 31;
    const int lhi  = lane >> 5;
    const int stoff = tid * 16;

    const char* bsrc = Wblob + (size_t)((g * 4 + nt) * 18) * 32768;

    const int arow = mt * 256 + wm * 64 + l31;
    const size_t aMc = (size_t)Mc;
#define AADDR(kt_, q_, i_, lo_) \
    (Ablob + (((size_t)((kt_) * 8 + (q_) * 2 + (lo_))) * aMc + (size_t)(arow + (i_) * 32)) * 16)

    const int brow = wn * 128 + l31;
    const int br7  = brow & 7;
#define BOFF(j_, q_) \
    ((size_t)(brow + (j_) * 32) * 128 + (size_t)(((q_) ^ br7) * 16))

#define STAGE(p_) \
    _Pragma("unroll") for (int i_ = 0; i_ < 4; ++i_) \
        gld16(sm + ((p_) & 3) * 32768 + i_ * 8192 + stoff, \
              bsrc + (size_t)(p_) * 32768 + i_ * 8192 + stoff);

#define LOADA(dst, kt_) \
    _Pragma("unroll") for (int ks_ = 0; ks_ < 2; ++ks_) \
    _Pragma("unroll") for (int i_ = 0; i_ < 2; ++i_) \
    _Pragma("unroll") for (int lo_ = 0; lo_ < 2; ++lo_) \
        dst[ks_][i_][lo_] = *(const f16x8*)AADDR(kt_, ks_ * 2 + lhi, i_, lo_);

#define KSTEP(bufp, par_, ks_, SET) do { \
    __builtin_amdgcn_s_setprio(1); \
    _Pragma("unroll") for (int j_ = 0; j_ < 4; ++j_) { \
        f16x8 wv = *(const f16x8*)((bufp) + BOFF(j_, (par_) * 4 + (ks_) * 2 + lhi)); \
        _Pragma("unroll") for (int i_ = 0; i_ < 2; ++i_) { \
            acc[i_][j_] = __builtin_amdgcn_mfma_f32_32x32x16_f16(SET[ks_][i_][0], wv, acc[i_][j_], 0, 0, 0); \
            acc[i_][j_] = __builtin_amdgcn_mfma_f32_32x32x16_f16(SET[ks_][i_][1], wv, acc[i_][j_], 0, 0, 0); \
        } } \
    __builtin_amdgcn_s_setprio(0); } while (0)

    f32x16 acc[2][4];
    #pragma unroll
    for (int i = 0; i < 2; ++i)
        #pragma unroll
        for (int j = 0; j < 4; ++j) acc[i][j] = (f32x16)0.f;

    f16x8 A0[2][2][2], A1[2][2][2];   // [kstep][i][isLo] — const-indexed only

    // prologue: stage pairs 0,1; load A(kt=0)
    STAGE(0); STAGE(1);
    LOADA(A0, 0);
    __builtin_amdgcn_sched_barrier(0);
    asm volatile("s_waitcnt vmcnt(12)" ::: "memory");  // pair0 in LDS; pair1+A in flight
    __builtin_amdgcn_sched_barrier(0);
    __builtin_amdgcn_s_barrier();

    for (int p = 0; p < 16; ++p) {
        const char* buf = sm + (p & 3) * 32768;

        STAGE(p + 2);                 // pad pairs 16,17 exist; never consumed
        LOADA(A1, 2 * p + 1);

        KSTEP(buf, 0, 0, A0);
        KSTEP(buf, 0, 1, A0);

        LOADA(A0, 2 * p + 2);         // p=15 reads 1-kt pad; never consumed

        KSTEP(buf, 1, 0, A1);
        KSTEP(buf, 1, 1, A1);

        // allowed outstanding = this pair's issues: stage 4 + 2x LOADA 16 = 20.
        // => pair(p+1)'s staging (issued at p-1) is drained before the barrier.
        __builtin_amdgcn_sched_barrier(0);
        asm volatile("s_waitcnt vmcnt(20)" ::: "memory");
        __builtin_amdgcn_sched_barrier(0);
        __builtin_amdgcn_s_barrier();
    }
#undef AADDR
#undef BOFF
#undef STAGE
#undef LOADA
#undef KSTEP

    // epilogue: C map (m74/m101): col=lane&31, row=(reg&3)+8*(reg>>2)+4*(lane>>5)
    const float* bias = (g == 0) ? bz : (g == 1) ? br : bh;
    float bcol[4];
    #pragma unroll
    for (int j = 0; j < 4; ++j) bcol[j] = bias[nt * 256 + wn * 128 + j * 32 + l31];

    _Float16* cbase = proj + (size_t)g * Mc * U + (size_t)(nt * 256 + wn * 128) + l31;
    #pragma unroll
    for (int i = 0; i < 2; ++i) {
        #pragma unroll
        for (int j = 0; j < 4; ++j) {
            #pragma unroll
            for (int reg = 0; reg < 16; ++reg) {
                const int row = mt * 256 + wm * 64 + i * 32 + (reg & 3) + 8 * (reg >> 2) + 4 * lhi;
                cbase[(size_t)row * U + j * 32] = (_Float16)(acc[i][j][reg] + bcol[j]);
            }
        }
    }
}

// ---------- scan: one thread per (b,u); 8-deep rotating register prefetch ----------
#define PF 8
__global__ __launch_bounds__(256)
void bru_scan(const _Float16* __restrict__ proj,
              const float* __restrict__ mz, const float* __restrict__ mr,
              float* __restrict__ out,
              float* __restrict__ hstate,
              int B, int T, int U, int Tc, int t0, int Mc)
{
    const int idx = blockIdx.x * blockDim.x + threadIdx.x;
    const int b = idx / U;
    const int u = idx - b * U;

    float h = (t0 == 0) ? 0.f : hstate[idx];
    const float vmz = mz[u];
    const float vmr = mr[u];

    const _Float16* pz = proj + (long)b * Tc * U + u;
    const _Float16* pr = pz + (long)Mc * U;
    const _Float16* ph = pr + (long)Mc * U;
    float* po = out + ((long)b * T + t0) * U + u;

    _Float16 fz[PF], fr[PF], fh[PF];
    #pragma unroll
    for (int i = 0; i < PF; ++i) {
        const long o = (long)((i < Tc) ? i : (Tc - 1)) * U;
        fz[i] = pz[o]; fr[i] = pr[o]; fh[i] = ph[o];
    }

    for (int t = 0; t < Tc; t += PF) {
        #pragma unroll
        for (int i = 0; i < PF; ++i) {
            const float xz = (float)fz[i];
            const float xr = (float)fr[i];
            const float xh = (float)fh[i];
            {
                int tn = t + i + PF; if (tn > Tc - 1) tn = Tc - 1;
                const long o = (long)tn * U;
                fz[i] = pz[o]; fr[i] = pr[o]; fh[i] = ph[o];
            }
            const float e2r = __expf(2.f * (xr + h * vmr));
            const float rr  = 2.f - 2.f / (e2r + 1.f);             // tanh(.)+1
            const float zz  = 1.f / (1.f + __expf(-(xz + h * vmz)));
            const float e2h = __expf(2.f * (xh + rr * h));
            const float hh  = 1.f - 2.f / (e2h + 1.f);             // tanh(.)
            h = (1.f - zz) * hh + zz * h;
            if (t + i < Tc) po[(long)(t + i) * U] = h;
        }
    }
    hstate[idx] = h;
}

// ---------- launch ----------
extern "C" void kernel_launch(void* const* d_in, const int* in_sizes, int n_in,
                              void* d_out, int out_size, void* d_ws, size_t ws_size,
                              hipStream_t stream)
{
    const float* x  = (const float*)d_in[0];
    const float* wz = (const float*)d_in[1];
    const float* wr = (const float*)d_in[2];
    const float* wh = (const float*)d_in[3];
    const float* mz = (const float*)d_in[4];
    const float* mr = (const float*)d_in[5];
    const float* bz = (const float*)d_in[6];
    const float* br = (const float*)d_in[7];
    const float* bh = (const float*)d_in[8];

    const int B = 64, T = 512, D = 1024, U = 1024;

    const size_t h_bytes = (size_t)B * U * sizeof(float);
    const size_t w_bytes = (size_t)12 * 18 * 32768;   // 7.08 MB, incl. 2-pair pad

    int Tc = T;
    while (Tc > 4) {
        const int Mc_ = B * Tc;
        const size_t a_bytes_ = (size_t)33 * 8 * Mc_ * 16;
        const size_t p_bytes_ = 3ull * Mc_ * U * sizeof(_Float16);
        if (h_bytes + w_bytes + a_bytes_ + p_bytes_ <= ws_size) break;
        Tc >>= 1;
    }
    const int nmt = B * Tc / 256;
    const int Mc  = B * Tc;
    const size_t a_bytes = (size_t)33 * 8 * Mc * 16;

    float*    h_state = (float*)d_ws;
    char*     Wblob   = (char*)d_ws + h_bytes;
    char*     Ablob   = (char*)d_ws + h_bytes + w_bytes;
    _Float16* proj    = (_Float16*)((char*)d_ws + h_bytes + w_bytes + a_bytes);

    bru_conv_w<<<3 * 4 * 16 * 2048 / 256, 256, 0, stream>>>(wz, wr, wh, Wblob, D, U);

    for (int t0 = 0; t0 < T; t0 += Tc) {
        bru_conv_a<<<(Mc * 32) / 256, 256, 0, stream>>>(x, Ablob, T, D, Tc, t0, Mc);

        bru_gemm_mfma<<<3 * nmt * 4, 512, 0, stream>>>(
            Ablob, Wblob, bz, br, bh, proj, nmt, U, Mc);

        bru_scan<<<(B * U) / 256, 256, 0, stream>>>(
            proj, mz, mr, (float*)d_out, h_state, B, T, U, Tc, t0, Mc);
    }
}